// Round 1
// 1424.629 us; speedup vs baseline: 1.0026x; 1.0026x over previous
//
#include <hip/hip_runtime.h>
#include <hip/hip_bf16.h>

// ---------------------------------------------------------------------------
// TransformerBlock: B=2 S=2048 D=1024 NH=16 HD=64 FF=4096
// Round 2: GEMMs switched to m97-style global_load_lds staging (linear LDS,
// width=16 direct-to-LDS DMA, 2-barrier loop) -- the proven 874-912 TF
// structure vs the previous register-staged ~646 TF structure.
// attn_write: float4 copy-out (HP 17->20 keeps 16B alignment).
// ---------------------------------------------------------------------------

constexpr int Bc = 2, Sc = 2048, Dc = 1024, NHc = 16, FFc = 4096;
constexpr int Mrows = Bc * Sc;              // 4096
constexpr float SCALE_ = 0.125f;            // HD^-0.5
constexpr float EPSc = 1e-5f;
constexpr float L2E = 1.4426950408889634f;
constexpr float SC_L2E = SCALE_ * L2E;

typedef __attribute__((ext_vector_type(8))) short short8;
typedef __attribute__((ext_vector_type(4))) short short4v;
typedef __attribute__((ext_vector_type(4))) float floatx4;

#define DEV static __device__ __forceinline__

DEV short f2b(float f) {                    // fp32 -> bf16 (RNE), raw bits
  union { float f; unsigned u; } v; v.f = f;
  unsigned r = v.u + 0x7FFFu + ((v.u >> 16) & 1u);
  return (short)(r >> 16);
}

DEV floatx4 mfma16(short8 a, short8 b, floatx4 c) {
  return __builtin_amdgcn_mfma_f32_16x16x32_bf16(a, b, c, 0, 0, 0);
}

// Direct global->LDS DMA, 16B per lane. LDS dest is wave-uniform base; HW
// writes base + lane*16. Global src is per-lane.
DEV void load_lds16(const short* g, short* l) {
  __builtin_amdgcn_global_load_lds(
      (const __attribute__((address_space(1))) void*)g,
      (__attribute__((address_space(3))) void*)l, 16, 0, 0);
}

// ---------------------------------------------------------------------------
// Weight cast + transpose: W (K,N) fp32 -> Wt (N,K) bf16
// ---------------------------------------------------------------------------
__global__ __launch_bounds__(256) void cast_transpose_k(
    const float* __restrict__ W, short* __restrict__ Wt, int K, int N) {
  __shared__ float t[32][33];
  int n0 = blockIdx.x * 32, k0 = blockIdx.y * 32;
  int tx = threadIdx.x & 31, ty = threadIdx.x >> 5;
  for (int r = ty; r < 32; r += 8)
    t[r][tx] = W[(size_t)(k0 + r) * N + n0 + tx];
  __syncthreads();
  for (int r = ty; r < 32; r += 8)
    Wt[(size_t)(n0 + r) * K + k0 + tx] = f2b(t[tx][r]);
}

// ---------------------------------------------------------------------------
// LayerNorm over D=1024, fp32 in -> bf16 out. One block (256 thr) per row.
// ---------------------------------------------------------------------------
__global__ __launch_bounds__(256) void layernorm_k(
    const float* __restrict__ x, const float* __restrict__ g,
    const float* __restrict__ bb, short* __restrict__ out) {
  int row = blockIdx.x;
  float4 v = ((const float4*)(x + (size_t)row * Dc))[threadIdx.x];
  float s = v.x + v.y + v.z + v.w;
  float s2 = v.x * v.x + v.y * v.y + v.z * v.z + v.w * v.w;
#pragma unroll
  for (int off = 32; off >= 1; off >>= 1) {
    s += __shfl_xor(s, off);
    s2 += __shfl_xor(s2, off);
  }
  __shared__ float red[8];
  int wave = threadIdx.x >> 6, lane = threadIdx.x & 63;
  if (lane == 0) { red[wave] = s; red[4 + wave] = s2; }
  __syncthreads();
  s = red[0] + red[1] + red[2] + red[3];
  s2 = red[4] + red[5] + red[6] + red[7];
  float mu = s * (1.0f / Dc);
  float var = s2 * (1.0f / Dc) - mu * mu;
  float rstd = rsqrtf(var + EPSc);
  int c = threadIdx.x * 4;
  float4 gv = ((const float4*)g)[threadIdx.x];
  float4 bv = ((const float4*)bb)[threadIdx.x];
  short4v o;
  o.x = f2b((v.x - mu) * rstd * gv.x + bv.x);
  o.y = f2b((v.y - mu) * rstd * gv.y + bv.y);
  o.z = f2b((v.z - mu) * rstd * gv.z + bv.z);
  o.w = f2b((v.w - mu) * rstd * gv.w + bv.w);
  *(short4v*)(out + (size_t)row * Dc + c) = o;
}

// ---------------------------------------------------------------------------
// GEMM: C(MxN) = A(MxK,bf16) @ Bt(NxK,bf16)^T  [+bias] [+resid fp32] [relu]
// m97 structure: 128x128 tile, BK=32, linear LDS [128][32], staged with
// global_load_lds width=16 (wave w, call c covers rows w*32+c*16..+16;
// lane l -> row +l/4, kchunk (l%4)*8shorts -- matches HW lane*16B layout).
// 4 waves -> 64x64 quadrants, 16x16x32 MFMA. OUTF==0: bf16, OUTF==1: fp32.
// ---------------------------------------------------------------------------
template <int OUTF>
__global__ __launch_bounds__(256) void gemm_bt_k(
    const short* __restrict__ A, const short* __restrict__ Bt,
    const float* __restrict__ bias, const float* __restrict__ resid,
    void* __restrict__ Cout, int M, int N, int K, int relu) {
  __shared__ short As[128 * 32];            // 8 KB, linear (global_load_lds)
  __shared__ short Bs[128 * 32];
  int tid = threadIdx.x;
  int wave = tid >> 6, lane = tid & 63, quad = lane >> 4, l16 = lane & 15;
  int m0 = blockIdx.y * 128, n0 = blockIdx.x * 128;
  int wm = (wave & 1) * 64, wn = (wave >> 1) * 64;
  int lrow = lane >> 2, lcol = (lane & 3) * 8;   // 16 rows x 4 chunks per call
  const short* Ab0 = A + (size_t)(m0 + wave * 32 + lrow) * K + lcol;
  const short* Ab1 = A + (size_t)(m0 + wave * 32 + 16 + lrow) * K + lcol;
  const short* Bb0 = Bt + (size_t)(n0 + wave * 32 + lrow) * K + lcol;
  const short* Bb1 = Bt + (size_t)(n0 + wave * 32 + 16 + lrow) * K + lcol;
  short* Al0 = &As[(wave * 2 + 0) * 512];
  short* Al1 = &As[(wave * 2 + 1) * 512];
  short* Bl0 = &Bs[(wave * 2 + 0) * 512];
  short* Bl1 = &Bs[(wave * 2 + 1) * 512];
  floatx4 acc[4][4] = {};
  for (int k0 = 0; k0 < K; k0 += 32) {
    __syncthreads();                        // prev tile's ds_reads done
    load_lds16(Ab0 + k0, Al0);
    load_lds16(Ab1 + k0, Al1);
    load_lds16(Bb0 + k0, Bl0);
    load_lds16(Bb1 + k0, Bl1);
    __syncthreads();                        // vmcnt(0) drain + all waves landed
    short8 af[4], bf[4];
#pragma unroll
    for (int i = 0; i < 4; ++i)
      af[i] = *(const short8*)(&As[(wm + i * 16 + l16) * 32 + quad * 8]);
#pragma unroll
    for (int j = 0; j < 4; ++j)
      bf[j] = *(const short8*)(&Bs[(wn + j * 16 + l16) * 32 + quad * 8]);
#pragma unroll
    for (int i = 0; i < 4; ++i)
#pragma unroll
      for (int j = 0; j < 4; ++j)
        acc[i][j] = mfma16(af[i], bf[j], acc[i][j]);
  }
#pragma unroll
  for (int i = 0; i < 4; ++i) {
    int row = m0 + wm + i * 16 + quad * 4;
#pragma unroll
    for (int j = 0; j < 4; ++j) {
      int col = n0 + wn + j * 16 + l16;
      float bv = bias ? bias[col] : 0.0f;
#pragma unroll
      for (int r = 0; r < 4; ++r) {
        float v = acc[i][j][r] + bv;
        if (resid) v += resid[(size_t)(row + r) * N + col];
        if (relu) v = fmaxf(v, 0.0f);
        if (OUTF == 0)
          ((short*)Cout)[(size_t)(row + r) * N + col] = f2b(v);
        else
          ((float*)Cout)[(size_t)(row + r) * N + col] = v;
      }
    }
  }
}

// ---------------------------------------------------------------------------
// vT[b][h][d][m] = kv[b][m][1024 + h*64 + d]   (bf16, for PV B-operand)
// ---------------------------------------------------------------------------
__global__ __launch_bounds__(256) void transpose_v_k(
    const short* __restrict__ kv, short* __restrict__ vT) {
  __shared__ short t[64][65];
  int bh = blockIdx.y, b = bh >> 4, h = bh & 15;
  int m0 = blockIdx.x * 64;
  int c = threadIdx.x & 63, ty = threadIdx.x >> 6;
  for (int r = ty; r < 64; r += 4)
    t[r][c] = kv[(size_t)(b * Sc + m0 + r) * 2048 + 1024 + h * 64 + c];
  __syncthreads();
  for (int dd = ty; dd < 64; dd += 4)
    vT[((size_t)bh * 64 + dd) * Sc + m0 + c] = t[c][dd];
}

// ---------------------------------------------------------------------------
// Attention pass 1: row max (log2-domain, incl. scale) + sumexp2 -> m_i, 1/l
// grid (S/64, B*NH); each wave owns 16 query rows, streams all m via MFMA.
// ---------------------------------------------------------------------------
__global__ __launch_bounds__(256) void attn_stats_k(
    const short* __restrict__ q, const short* __restrict__ kv,
    float* __restrict__ m_i, float* __restrict__ inv_l) {
  int bh = blockIdx.y, b = bh >> 4, h = bh & 15;
  int wave = threadIdx.x >> 6, lane = threadIdx.x & 63, quad = lane >> 4,
      l16 = lane & 15;
  int n0 = blockIdx.x * 64 + wave * 16;
  const short* qp = q + (size_t)(b * Sc + n0 + l16) * Dc + h * 64 + quad * 8;
  short8 qf0 = *(const short8*)qp;
  short8 qf1 = *(const short8*)(qp + 32);
  const short* kb = kv + (size_t)b * Sc * 2048 + h * 64 + quad * 8;
  float rm[4], rl[4];
#pragma unroll
  for (int r = 0; r < 4; ++r) { rm[r] = -1e30f; rl[r] = 0.0f; }
  for (int m0 = 0; m0 < Sc; m0 += 16) {
    const short* kp = kb + (size_t)(m0 + l16) * 2048;
    short8 kf0 = *(const short8*)kp;
    short8 kf1 = *(const short8*)(kp + 32);
    floatx4 s = {0.0f, 0.0f, 0.0f, 0.0f};
    s = mfma16(qf0, kf0, s);
    s = mfma16(qf1, kf1, s);
#pragma unroll
    for (int r = 0; r < 4; ++r) {
      float sv = s[r] * SC_L2E;
      if (sv <= rm[r]) {
        rl[r] += exp2f(sv - rm[r]);
      } else {
        rl[r] = rl[r] * exp2f(rm[r] - sv) + 1.0f;
        rm[r] = sv;
      }
    }
  }
#pragma unroll
  for (int off = 1; off < 16; off <<= 1) {
#pragma unroll
    for (int r = 0; r < 4; ++r) {
      float om = __shfl_xor(rm[r], off);
      float ol = __shfl_xor(rl[r], off);
      float nm = fmaxf(rm[r], om);
      rl[r] = rl[r] * exp2f(rm[r] - nm) + ol * exp2f(om - nm);
      rm[r] = nm;
    }
  }
  if (l16 == 0) {
    int n = n0 + quad * 4;
#pragma unroll
    for (int r = 0; r < 4; ++r) {
      m_i[(size_t)bh * Sc + n + r] = rm[r];
      inv_l[(size_t)bh * Sc + n + r] = 1.0f / rl[r];
    }
  }
}

// ---------------------------------------------------------------------------
// Attention pass 2a: write attn[b][n][m][h] fp32, coalesced.
// Block covers (b, n-tile 32, m-tile 16, ALL 16 heads); wave w -> heads 4w..4w+3.
// P gathered in LDS [n][m][h] (HP=20 -> 80B rows, 16B aligned) then stored
// as float4: 1 KB contiguous per wave-instruction.
// ---------------------------------------------------------------------------
__global__ __launch_bounds__(256) void attn_write_k(
    const short* __restrict__ q, const short* __restrict__ kv,
    const float* __restrict__ m_i, const float* __restrict__ inv_l,
    float* __restrict__ attn) {
  constexpr int HP = 20;
  __shared__ float P[32 * 16 * HP];         // 40960 B
  __shared__ float sm[16][32], sl[16][32];  // stats for n0..n0+31, all h
  int b = blockIdx.z;
  int n0 = blockIdx.y * 32, m0 = blockIdx.x * 16;
  int tid = threadIdx.x;
  int wave = tid >> 6, lane = tid & 63, quad = lane >> 4, l16 = lane & 15;
  for (int i = tid; i < 512; i += 256) {
    int h = i >> 5, nn = i & 31;
    sm[h][nn] = m_i[(size_t)(b * 16 + h) * Sc + n0 + nn];
    sl[h][nn] = inv_l[(size_t)(b * 16 + h) * Sc + n0 + nn];
  }
  __syncthreads();
#pragma unroll
  for (int hh = 0; hh < 4; ++hh) {
    int h = wave * 4 + hh;
    const short* kp = kv + (size_t)(b * Sc + m0 + l16) * 2048 + h * 64 + quad * 8;
    short8 kf0 = *(const short8*)kp;
    short8 kf1 = *(const short8*)(kp + 32);
#pragma unroll
    for (int ni = 0; ni < 2; ++ni) {
      const short* qp =
          q + (size_t)(b * Sc + n0 + ni * 16 + l16) * Dc + h * 64 + quad * 8;
      short8 qf0 = *(const short8*)qp;
      short8 qf1 = *(const short8*)(qp + 32);
      floatx4 s = {0.0f, 0.0f, 0.0f, 0.0f};
      s = mfma16(qf0, kf0, s);
      s = mfma16(qf1, kf1, s);
#pragma unroll
      for (int r = 0; r < 4; ++r) {
        int nn = ni * 16 + quad * 4 + r;
        float p = exp2f(s[r] * SC_L2E - sm[h][nn]) * sl[h][nn];
        P[(nn * 16 + l16) * HP + h] = p;
      }
    }
  }
  __syncthreads();
  size_t base = ((size_t)(b * Sc + n0) * Sc + m0) * 16;
  int w = tid >> 6, l = tid & 63;
  int ml = l >> 2, h4 = (l & 3) * 4;        // one wave = one n-row (1 KB)
  for (int n = w; n < 32; n += 4) {
    float4 v = *(const float4*)&P[(n * 16 + ml) * HP + h4];
    *(float4*)&attn[base + (size_t)n * (Sc * 16) + ml * 16 + h4] = v;
  }
}

// ---------------------------------------------------------------------------
// Attention pass 2b: o[b][n][h*64+d] = softmax(qk) @ v, per (b,h); recompute S,
// P via per-wave LDS C->A layout round-trip, PV with vT. inv_l folded at end.
// ---------------------------------------------------------------------------
__global__ __launch_bounds__(256) void attn_pv_k(
    const short* __restrict__ q, const short* __restrict__ kv,
    const short* __restrict__ vT, const float* __restrict__ m_i,
    const float* __restrict__ inv_l, short* __restrict__ o) {
  constexpr int PPAD = 40;                  // 80B rows, 16B aligned
  __shared__ short P[4][16 * PPAD];
  int bh = blockIdx.y, b = bh >> 4, h = bh & 15;
  int wave = threadIdx.x >> 6, lane = threadIdx.x & 63, quad = lane >> 4,
      l16 = lane & 15;
  int n0 = blockIdx.x * 64 + wave * 16;
  const short* qp = q + (size_t)(b * Sc + n0 + l16) * Dc + h * 64 + quad * 8;
  short8 qf0 = *(const short8*)qp;
  short8 qf1 = *(const short8*)(qp + 32);
  float mm[4], il[4];
#pragma unroll
  for (int r = 0; r < 4; ++r) {
    int n = n0 + quad * 4 + r;
    mm[r] = m_i[(size_t)bh * Sc + n];
    il[r] = inv_l[(size_t)bh * Sc + n];
  }
  floatx4 oacc[4] = {};
  const short* kb = kv + (size_t)b * Sc * 2048 + h * 64 + quad * 8;
  const short* vb = vT + (size_t)bh * 64 * Sc;
  short* myP = &P[wave][0];
  for (int m0 = 0; m0 < Sc; m0 += 32) {
#pragma unroll
    for (int ms = 0; ms < 2; ++ms) {
      const short* kp = kb + (size_t)(m0 + ms * 16 + l16) * 2048;
      short8 kf0 = *(const short8*)kp;
      short8 kf1 = *(const short8*)(kp + 32);
      floatx4 s = {0.0f, 0.0f, 0.0f, 0.0f};
      s = mfma16(qf0, kf0, s);
      s = mfma16(qf1, kf1, s);
#pragma unroll
      for (int r = 0; r < 4; ++r) {
        float p = exp2f(s[r] * SC_L2E - mm[r]);  // <= 1, unnormalized
        myP[(quad * 4 + r) * PPAD + ms * 16 + l16] = f2b(p);
      }
    }
    short8 pf = *(const short8*)(&myP[l16 * PPAD + quad * 8]);
#pragma unroll
    for (int ds = 0; ds < 4; ++ds) {
      short8 vf = *(const short8*)(vb + (size_t)(ds * 16 + l16) * Sc + m0 + quad * 8);
      oacc[ds] = mfma16(pf, vf, oacc[ds]);
    }
  }
#pragma unroll
  for (int ds = 0; ds < 4; ++ds)
#pragma unroll
    for (int r = 0; r < 4; ++r)
      o[(size_t)(b * Sc + n0 + quad * 4 + r) * Dc + h * 64 + ds * 16 + l16] =
          f2b(oacc[ds][r] * il[r]);
}

// ---------------------------------------------------------------------------
extern "C" void kernel_launch(void* const* d_in, const int* in_sizes, int n_in,
                              void* d_out, int out_size, void* d_ws,
                              size_t ws_size, hipStream_t stream) {
  const float* x = (const float*)d_in[0];
  const float* ln1g = (const float*)d_in[1];
  const float* ln1b = (const float*)d_in[2];
  const float* wq = (const float*)d_in[3];
  const float* wkv = (const float*)d_in[4];
  const float* wo = (const float*)d_in[5];
  const float* bo = (const float*)d_in[6];
  const float* ln2g = (const float*)d_in[7];
  const float* ln2b = (const float*)d_in[8];
  const float* w1 = (const float*)d_in[9];
  const float* b1 = (const float*)d_in[10];
  const float* w2 = (const float*)d_in[11];
  const float* b2 = (const float*)d_in[12];

  char* ws = (char*)d_ws;
  const size_t MB = 1024 * 1024;
  short* wqT  = (short*)(ws + 0 * MB);       // 2 MB
  short* wkvT = (short*)(ws + 2 * MB);       // 4 MB
  short* woT  = (short*)(ws + 6 * MB);       // 2 MB
  short* w1T  = (short*)(ws + 8 * MB);       // 8 MB
  short* w2T  = (short*)(ws + 16 * MB);      // 8 MB
  short* h    = (short*)(ws + 24 * MB);      // 8 MB (reused as h2)
  float* x2   = (float*)(ws + 32 * MB);      // 16 MB
  float* m_i  = (float*)(ws + 48 * MB);      // 256 KB
  float* invl = (float*)(ws + 48 * MB + 256 * 1024);  // 256 KB
  short* o    = (short*)(ws + 49 * MB);      // 8 MB
  short* qb   = (short*)(ws + 57 * MB);      // 8 MB  -+
  short* kvb  = (short*)(ws + 65 * MB);      // 16 MB  | overlaid by ff1 later
  short* vT   = (short*)(ws + 81 * MB);      // 8 MB  -+
  short* ff1  = (short*)(ws + 57 * MB);      // 32 MB (after attention done)

  float* out0 = (float*)d_out;
  float* attn = (float*)d_out + (size_t)Bc * Sc * Dc;

  // weights -> bf16, transposed (N x K)
  cast_transpose_k<<<dim3(Dc / 32, Dc / 32), 256, 0, stream>>>(wq, wqT, Dc, Dc);
  cast_transpose_k<<<dim3(2048 / 32, Dc / 32), 256, 0, stream>>>(wkv, wkvT, Dc, 2048);
  cast_transpose_k<<<dim3(Dc / 32, Dc / 32), 256, 0, stream>>>(wo, woT, Dc, Dc);
  cast_transpose_k<<<dim3(FFc / 32, Dc / 32), 256, 0, stream>>>(w1, w1T, Dc, FFc);
  cast_transpose_k<<<dim3(Dc / 32, FFc / 32), 256, 0, stream>>>(w2, w2T, FFc, Dc);

  layernorm_k<<<Mrows, 256, 0, stream>>>(x, ln1g, ln1b, h);

  gemm_bt_k<0><<<dim3(Dc / 128, Mrows / 128), 256, 0, stream>>>(
      h, wqT, nullptr, nullptr, qb, Mrows, Dc, Dc, 0);
  gemm_bt_k<0><<<dim3(2048 / 128, Mrows / 128), 256, 0, stream>>>(
      h, wkvT, nullptr, nullptr, kvb, Mrows, 2048, Dc, 0);

  transpose_v_k<<<dim3(Sc / 64, Bc * NHc), 256, 0, stream>>>(kvb, vT);
  attn_stats_k<<<dim3(Sc / 64, Bc * NHc), 256, 0, stream>>>(qb, kvb, m_i, invl);
  attn_write_k<<<dim3(Sc / 16, Sc / 32, Bc), 256, 0, stream>>>(qb, kvb, m_i, invl, attn);
  attn_pv_k<<<dim3(Sc / 64, Bc * NHc), 256, 0, stream>>>(qb, kvb, vT, m_i, invl, o);

  gemm_bt_k<1><<<dim3(Dc / 128, Mrows / 128), 256, 0, stream>>>(
      o, woT, bo, x, x2, Mrows, Dc, Dc, 0);
  layernorm_k<<<Mrows, 256, 0, stream>>>(x2, ln2g, ln2b, h);
  gemm_bt_k<0><<<dim3(FFc / 128, Mrows / 128), 256, 0, stream>>>(
      h, w1T, b1, nullptr, ff1, Mrows, FFc, Dc, 1);
  gemm_bt_k<1><<<dim3(Dc / 128, Mrows / 128), 256, 0, stream>>>(
      ff1, w2T, b2, x2, out0, Mrows, Dc, FFc, 0);
}

// Round 2
// 1278.550 us; speedup vs baseline: 1.1171x; 1.1143x over previous
//
#include <hip/hip_runtime.h>
#include <hip/hip_bf16.h>

// ---------------------------------------------------------------------------
// TransformerBlock: B=2 S=2048 D=1024 NH=16 HD=64 FF=4096
// Round 3: attention restructured 3-pass -> 2-pass. attn_fused_k computes S
// ONCE per (n,m) tile: writes normalized fp32 P to attn (coalesced 1KB
// stores) AND accumulates PV from a per-wave bf16 P staging buffer.
// m-chunked x4 for occupancy; partial O reduced by opart_reduce_k.
// GEMMs: m97-style global_load_lds staging (unchanged from round 2).
// ---------------------------------------------------------------------------

constexpr int Bc = 2, Sc = 2048, Dc = 1024, NHc = 16, FFc = 4096;
constexpr int Mrows = Bc * Sc;              // 4096
constexpr float SCALE_ = 0.125f;            // HD^-0.5
constexpr float EPSc = 1e-5f;
constexpr float L2E = 1.4426950408889634f;
constexpr float SC_L2E = SCALE_ * L2E;

typedef __attribute__((ext_vector_type(8))) short short8;
typedef __attribute__((ext_vector_type(4))) short short4v;
typedef __attribute__((ext_vector_type(4))) float floatx4;

#define DEV static __device__ __forceinline__

DEV short f2b(float f) {                    // fp32 -> bf16 (RNE), raw bits
  union { float f; unsigned u; } v; v.f = f;
  unsigned r = v.u + 0x7FFFu + ((v.u >> 16) & 1u);
  return (short)(r >> 16);
}

DEV floatx4 mfma16(short8 a, short8 b, floatx4 c) {
  return __builtin_amdgcn_mfma_f32_16x16x32_bf16(a, b, c, 0, 0, 0);
}

// Direct global->LDS DMA, 16B per lane. LDS dest is wave-uniform base; HW
// writes base + lane*16. Global src is per-lane.
DEV void load_lds16(const short* g, short* l) {
  __builtin_amdgcn_global_load_lds(
      (const __attribute__((address_space(1))) void*)g,
      (__attribute__((address_space(3))) void*)l, 16, 0, 0);
}

// ---------------------------------------------------------------------------
// Weight cast + transpose: W (K,N) fp32 -> Wt (N,K) bf16
// ---------------------------------------------------------------------------
__global__ __launch_bounds__(256) void cast_transpose_k(
    const float* __restrict__ W, short* __restrict__ Wt, int K, int N) {
  __shared__ float t[32][33];
  int n0 = blockIdx.x * 32, k0 = blockIdx.y * 32;
  int tx = threadIdx.x & 31, ty = threadIdx.x >> 5;
  for (int r = ty; r < 32; r += 8)
    t[r][tx] = W[(size_t)(k0 + r) * N + n0 + tx];
  __syncthreads();
  for (int r = ty; r < 32; r += 8)
    Wt[(size_t)(n0 + r) * K + k0 + tx] = f2b(t[tx][r]);
}

// ---------------------------------------------------------------------------
// LayerNorm over D=1024, fp32 in -> bf16 out. One block (256 thr) per row.
// ---------------------------------------------------------------------------
__global__ __launch_bounds__(256) void layernorm_k(
    const float* __restrict__ x, const float* __restrict__ g,
    const float* __restrict__ bb, short* __restrict__ out) {
  int row = blockIdx.x;
  float4 v = ((const float4*)(x + (size_t)row * Dc))[threadIdx.x];
  float s = v.x + v.y + v.z + v.w;
  float s2 = v.x * v.x + v.y * v.y + v.z * v.z + v.w * v.w;
#pragma unroll
  for (int off = 32; off >= 1; off >>= 1) {
    s += __shfl_xor(s, off);
    s2 += __shfl_xor(s2, off);
  }
  __shared__ float red[8];
  int wave = threadIdx.x >> 6, lane = threadIdx.x & 63;
  if (lane == 0) { red[wave] = s; red[4 + wave] = s2; }
  __syncthreads();
  s = red[0] + red[1] + red[2] + red[3];
  s2 = red[4] + red[5] + red[6] + red[7];
  float mu = s * (1.0f / Dc);
  float var = s2 * (1.0f / Dc) - mu * mu;
  float rstd = rsqrtf(var + EPSc);
  int c = threadIdx.x * 4;
  float4 gv = ((const float4*)g)[threadIdx.x];
  float4 bv = ((const float4*)bb)[threadIdx.x];
  short4v o;
  o.x = f2b((v.x - mu) * rstd * gv.x + bv.x);
  o.y = f2b((v.y - mu) * rstd * gv.y + bv.y);
  o.z = f2b((v.z - mu) * rstd * gv.z + bv.z);
  o.w = f2b((v.w - mu) * rstd * gv.w + bv.w);
  *(short4v*)(out + (size_t)row * Dc + c) = o;
}

// ---------------------------------------------------------------------------
// GEMM: C(MxN) = A(MxK,bf16) @ Bt(NxK,bf16)^T  [+bias] [+resid fp32] [relu]
// m97 structure: 128x128 tile, BK=32, linear LDS, global_load_lds width=16.
// ---------------------------------------------------------------------------
template <int OUTF>
__global__ __launch_bounds__(256) void gemm_bt_k(
    const short* __restrict__ A, const short* __restrict__ Bt,
    const float* __restrict__ bias, const float* __restrict__ resid,
    void* __restrict__ Cout, int M, int N, int K, int relu) {
  __shared__ short As[128 * 32];            // 8 KB, linear (global_load_lds)
  __shared__ short Bs[128 * 32];
  int tid = threadIdx.x;
  int wave = tid >> 6, lane = tid & 63, quad = lane >> 4, l16 = lane & 15;
  int m0 = blockIdx.y * 128, n0 = blockIdx.x * 128;
  int wm = (wave & 1) * 64, wn = (wave >> 1) * 64;
  int lrow = lane >> 2, lcol = (lane & 3) * 8;   // 16 rows x 4 chunks per call
  const short* Ab0 = A + (size_t)(m0 + wave * 32 + lrow) * K + lcol;
  const short* Ab1 = A + (size_t)(m0 + wave * 32 + 16 + lrow) * K + lcol;
  const short* Bb0 = Bt + (size_t)(n0 + wave * 32 + lrow) * K + lcol;
  const short* Bb1 = Bt + (size_t)(n0 + wave * 32 + 16 + lrow) * K + lcol;
  short* Al0 = &As[(wave * 2 + 0) * 512];
  short* Al1 = &As[(wave * 2 + 1) * 512];
  short* Bl0 = &Bs[(wave * 2 + 0) * 512];
  short* Bl1 = &Bs[(wave * 2 + 1) * 512];
  floatx4 acc[4][4] = {};
  for (int k0 = 0; k0 < K; k0 += 32) {
    __syncthreads();                        // prev tile's ds_reads done
    load_lds16(Ab0 + k0, Al0);
    load_lds16(Ab1 + k0, Al1);
    load_lds16(Bb0 + k0, Bl0);
    load_lds16(Bb1 + k0, Bl1);
    __syncthreads();                        // vmcnt(0) drain + all waves landed
    short8 af[4], bf[4];
#pragma unroll
    for (int i = 0; i < 4; ++i)
      af[i] = *(const short8*)(&As[(wm + i * 16 + l16) * 32 + quad * 8]);
#pragma unroll
    for (int j = 0; j < 4; ++j)
      bf[j] = *(const short8*)(&Bs[(wn + j * 16 + l16) * 32 + quad * 8]);
#pragma unroll
    for (int i = 0; i < 4; ++i)
#pragma unroll
      for (int j = 0; j < 4; ++j)
        acc[i][j] = mfma16(af[i], bf[j], acc[i][j]);
  }
#pragma unroll
  for (int i = 0; i < 4; ++i) {
    int row = m0 + wm + i * 16 + quad * 4;
#pragma unroll
    for (int j = 0; j < 4; ++j) {
      int col = n0 + wn + j * 16 + l16;
      float bv = bias ? bias[col] : 0.0f;
#pragma unroll
      for (int r = 0; r < 4; ++r) {
        float v = acc[i][j][r] + bv;
        if (resid) v += resid[(size_t)(row + r) * N + col];
        if (relu) v = fmaxf(v, 0.0f);
        if (OUTF == 0)
          ((short*)Cout)[(size_t)(row + r) * N + col] = f2b(v);
        else
          ((float*)Cout)[(size_t)(row + r) * N + col] = v;
      }
    }
  }
}

// ---------------------------------------------------------------------------
// vT[b][h][d][m] = kv[b][m][1024 + h*64 + d]   (bf16, for PV B-operand)
// ---------------------------------------------------------------------------
__global__ __launch_bounds__(256) void transpose_v_k(
    const short* __restrict__ kv, short* __restrict__ vT) {
  __shared__ short t[64][65];
  int bh = blockIdx.y, b = bh >> 4, h = bh & 15;
  int m0 = blockIdx.x * 64;
  int c = threadIdx.x & 63, ty = threadIdx.x >> 6;
  for (int r = ty; r < 64; r += 4)
    t[r][c] = kv[(size_t)(b * Sc + m0 + r) * 2048 + 1024 + h * 64 + c];
  __syncthreads();
  for (int dd = ty; dd < 64; dd += 4)
    vT[((size_t)bh * 64 + dd) * Sc + m0 + c] = t[c][dd];
}

// ---------------------------------------------------------------------------
// Attention pass 1: row max (log2-domain, incl. scale) + sumexp2 -> m_i, 1/l
// ---------------------------------------------------------------------------
__global__ __launch_bounds__(256) void attn_stats_k(
    const short* __restrict__ q, const short* __restrict__ kv,
    float* __restrict__ m_i, float* __restrict__ inv_l) {
  int bh = blockIdx.y, b = bh >> 4, h = bh & 15;
  int wave = threadIdx.x >> 6, lane = threadIdx.x & 63, quad = lane >> 4,
      l16 = lane & 15;
  int n0 = blockIdx.x * 64 + wave * 16;
  const short* qp = q + (size_t)(b * Sc + n0 + l16) * Dc + h * 64 + quad * 8;
  short8 qf0 = *(const short8*)qp;
  short8 qf1 = *(const short8*)(qp + 32);
  const short* kb = kv + (size_t)b * Sc * 2048 + h * 64 + quad * 8;
  float rm[4], rl[4];
#pragma unroll
  for (int r = 0; r < 4; ++r) { rm[r] = -1e30f; rl[r] = 0.0f; }
  for (int m0 = 0; m0 < Sc; m0 += 16) {
    const short* kp = kb + (size_t)(m0 + l16) * 2048;
    short8 kf0 = *(const short8*)kp;
    short8 kf1 = *(const short8*)(kp + 32);
    floatx4 s = {0.0f, 0.0f, 0.0f, 0.0f};
    s = mfma16(qf0, kf0, s);
    s = mfma16(qf1, kf1, s);
#pragma unroll
    for (int r = 0; r < 4; ++r) {
      float sv = s[r] * SC_L2E;
      if (sv <= rm[r]) {
        rl[r] += exp2f(sv - rm[r]);
      } else {
        rl[r] = rl[r] * exp2f(rm[r] - sv) + 1.0f;
        rm[r] = sv;
      }
    }
  }
#pragma unroll
  for (int off = 1; off < 16; off <<= 1) {
#pragma unroll
    for (int r = 0; r < 4; ++r) {
      float om = __shfl_xor(rm[r], off);
      float ol = __shfl_xor(rl[r], off);
      float nm = fmaxf(rm[r], om);
      rl[r] = rl[r] * exp2f(rm[r] - nm) + ol * exp2f(om - nm);
      rm[r] = nm;
    }
  }
  if (l16 == 0) {
    int n = n0 + quad * 4;
#pragma unroll
    for (int r = 0; r < 4; ++r) {
      m_i[(size_t)bh * Sc + n + r] = rm[r];
      inv_l[(size_t)bh * Sc + n + r] = 1.0f / rl[r];
    }
  }
}

// ---------------------------------------------------------------------------
// Attention pass 2 (fused): per block (b, 16 n-rows, ALL 16 heads, m-chunk of
// 512). Computes S ONCE per tile: P = exp2(S*c - m)*inv_l (normalized),
// -> fp32 LDS [n][m][h] for coalesced attn stores (1KB/wave-instr)
// -> bf16 per-wave staging for the PV A-fragment; O accumulated per m-chunk,
// partials summed by opart_reduce_k.
// LDS: 40960 (P) + 5120 (pw) + 2048 (stats) = 48128 B -> 3 blocks/CU.
// ---------------------------------------------------------------------------
__global__ __launch_bounds__(256) void attn_fused_k(
    const short* __restrict__ q, const short* __restrict__ kv,
    const short* __restrict__ vT, const float* __restrict__ m_i,
    const float* __restrict__ inv_l, float* __restrict__ attn,
    float* __restrict__ opart) {
  constexpr int HP = 20;                    // h-dim pad: 80B rows, f4-aligned
  __shared__ float P[16 * 32 * HP];         // [nn][m][h] 40960 B
  __shared__ short pw[4][16 * 40];          // per-wave bf16 P (A-frag staging)
  __shared__ float sm[16][16], sl[16][16];
  int b = blockIdx.z, mc = blockIdx.x;
  int n0 = blockIdx.y * 16;
  int tid = threadIdx.x;
  int wave = tid >> 6, lane = tid & 63, quad = lane >> 4, l16 = lane & 15;
  {
    int h = tid >> 4, nn = tid & 15;
    sm[h][nn] = m_i[(size_t)(b * 16 + h) * Sc + n0 + nn];
    sl[h][nn] = inv_l[(size_t)(b * 16 + h) * Sc + n0 + nn];
  }
  short8 qf[4][2];
#pragma unroll
  for (int hh = 0; hh < 4; ++hh) {
    const short* qp =
        q + (size_t)(b * Sc + n0 + l16) * Dc + (wave * 4 + hh) * 64 + quad * 8;
    qf[hh][0] = *(const short8*)qp;
    qf[hh][1] = *(const short8*)(qp + 32);
  }
  floatx4 oacc[4][4] = {};
  short* myP = &pw[wave][0];
  __syncthreads();
  int mend = mc * 512 + 512;
  for (int m0 = mc * 512; m0 < mend; m0 += 32) {
#pragma unroll
    for (int hh = 0; hh < 4; ++hh) {
      int h = wave * 4 + hh;
      const short* kb =
          kv + (size_t)(b * Sc + m0 + l16) * 2048 + h * 64 + quad * 8;
#pragma unroll
      for (int ms = 0; ms < 2; ++ms) {
        const short* kp = kb + (size_t)ms * 16 * 2048;
        short8 kf0 = *(const short8*)kp;
        short8 kf1 = *(const short8*)(kp + 32);
        floatx4 s = {0.0f, 0.0f, 0.0f, 0.0f};
        s = mfma16(qf[hh][0], kf0, s);
        s = mfma16(qf[hh][1], kf1, s);
#pragma unroll
        for (int r = 0; r < 4; ++r) {
          int nn = quad * 4 + r;
          float p = exp2f(s[r] * SC_L2E - sm[h][nn]) * sl[h][nn];
          P[(nn * 32 + ms * 16 + l16) * HP + h] = p;
          myP[nn * 40 + ms * 16 + l16] = f2b(p);
        }
      }
      short8 pa = *(const short8*)(&myP[l16 * 40 + quad * 8]);
      const short* vb = vT + ((size_t)(b * 16 + h) * 64) * Sc;
#pragma unroll
      for (int dt = 0; dt < 4; ++dt) {
        short8 vf =
            *(const short8*)(vb + (size_t)(dt * 16 + l16) * Sc + m0 + quad * 8);
        oacc[hh][dt] = mfma16(pa, vf, oacc[hh][dt]);
      }
    }
    __syncthreads();                        // all waves' P[h] slots landed
    size_t base = (((size_t)b * Sc + n0) * Sc + m0) * 16;
    for (int t = tid; t < 2048; t += 256) { // 16n x 32m x 4 h-groups
      int nn = t >> 7, rem = t & 127;
      int ml = rem >> 2, h4 = (rem & 3) * 4;
      float4 v = *(const float4*)&P[(nn * 32 + ml) * HP + h4];
      *(float4*)&attn[base + (size_t)nn * (Sc * 16) + ml * 16 + h4] = v;
    }
    __syncthreads();                        // P free for next m-tile
  }
  float* op = opart + (size_t)mc * ((size_t)Bc * Sc * Dc) +
              ((size_t)b * Sc + n0) * Dc;
#pragma unroll
  for (int hh = 0; hh < 4; ++hh)
#pragma unroll
    for (int dt = 0; dt < 4; ++dt)
#pragma unroll
      for (int r = 0; r < 4; ++r)
        op[(size_t)(quad * 4 + r) * Dc + (wave * 4 + hh) * 64 + dt * 16 + l16] =
            oacc[hh][dt][r];
}

// ---------------------------------------------------------------------------
// O = sum of 4 m-chunk partials, fp32 -> bf16
// ---------------------------------------------------------------------------
__global__ __launch_bounds__(256) void opart_reduce_k(
    const float* __restrict__ op, short* __restrict__ o) {
  const size_t PS = (size_t)Bc * Sc * Dc;   // 4M floats per partial
  const size_t n4 = PS / 4;
  for (size_t i = (size_t)blockIdx.x * 256 + threadIdx.x; i < n4;
       i += (size_t)gridDim.x * 256) {
    float4 a = ((const float4*)op)[i];
    float4 b = ((const float4*)(op + PS))[i];
    float4 c = ((const float4*)(op + 2 * PS))[i];
    float4 d = ((const float4*)(op + 3 * PS))[i];
    short4v s;
    s.x = f2b(a.x + b.x + c.x + d.x);
    s.y = f2b(a.y + b.y + c.y + d.y);
    s.z = f2b(a.z + b.z + c.z + d.z);
    s.w = f2b(a.w + b.w + c.w + d.w);
    ((short4v*)o)[i] = s;
  }
}

// ---------------------------------------------------------------------------
extern "C" void kernel_launch(void* const* d_in, const int* in_sizes, int n_in,
                              void* d_out, int out_size, void* d_ws,
                              size_t ws_size, hipStream_t stream) {
  const float* x = (const float*)d_in[0];
  const float* ln1g = (const float*)d_in[1];
  const float* ln1b = (const float*)d_in[2];
  const float* wq = (const float*)d_in[3];
  const float* wkv = (const float*)d_in[4];
  const float* wo = (const float*)d_in[5];
  const float* bo = (const float*)d_in[6];
  const float* ln2g = (const float*)d_in[7];
  const float* ln2b = (const float*)d_in[8];
  const float* w1 = (const float*)d_in[9];
  const float* b1 = (const float*)d_in[10];
  const float* w2 = (const float*)d_in[11];
  const float* b2 = (const float*)d_in[12];

  char* ws = (char*)d_ws;
  const size_t MB = 1024 * 1024;
  short* wqT  = (short*)(ws + 0 * MB);       // 2 MB
  short* wkvT = (short*)(ws + 2 * MB);       // 4 MB
  short* woT  = (short*)(ws + 6 * MB);       // 2 MB
  short* w1T  = (short*)(ws + 8 * MB);       // 8 MB
  short* w2T  = (short*)(ws + 16 * MB);      // 8 MB
  short* h    = (short*)(ws + 24 * MB);      // 8 MB (reused as h2)
  float* x2   = (float*)(ws + 32 * MB);      // 16 MB
  float* m_i  = (float*)(ws + 48 * MB);      // 256 KB
  float* invl = (float*)(ws + 48 * MB + 256 * 1024);  // 256 KB
  short* o    = (short*)(ws + 49 * MB);      // 8 MB
  short* qb   = (short*)(ws + 57 * MB);      // 8 MB  -+
  short* kvb  = (short*)(ws + 65 * MB);      // 16 MB  | overlaid by ff1 later
  short* vT   = (short*)(ws + 81 * MB);      // 8 MB  -+
  float* opart= (float*)(ws + 96 * MB);      // 64 MB (4 x 16 MB O partials)
  short* ff1  = (short*)(ws + 57 * MB);      // 32 MB (after attention done)

  float* out0 = (float*)d_out;
  float* attn = (float*)d_out + (size_t)Bc * Sc * Dc;

  // weights -> bf16, transposed (N x K)
  cast_transpose_k<<<dim3(Dc / 32, Dc / 32), 256, 0, stream>>>(wq, wqT, Dc, Dc);
  cast_transpose_k<<<dim3(2048 / 32, Dc / 32), 256, 0, stream>>>(wkv, wkvT, Dc, 2048);
  cast_transpose_k<<<dim3(Dc / 32, Dc / 32), 256, 0, stream>>>(wo, woT, Dc, Dc);
  cast_transpose_k<<<dim3(FFc / 32, Dc / 32), 256, 0, stream>>>(w1, w1T, Dc, FFc);
  cast_transpose_k<<<dim3(Dc / 32, FFc / 32), 256, 0, stream>>>(w2, w2T, FFc, Dc);

  layernorm_k<<<Mrows, 256, 0, stream>>>(x, ln1g, ln1b, h);

  gemm_bt_k<0><<<dim3(Dc / 128, Mrows / 128), 256, 0, stream>>>(
      h, wqT, nullptr, nullptr, qb, Mrows, Dc, Dc, 0);
  gemm_bt_k<0><<<dim3(2048 / 128, Mrows / 128), 256, 0, stream>>>(
      h, wkvT, nullptr, nullptr, kvb, Mrows, 2048, Dc, 0);

  transpose_v_k<<<dim3(Sc / 64, Bc * NHc), 256, 0, stream>>>(kvb, vT);
  attn_stats_k<<<dim3(Sc / 64, Bc * NHc), 256, 0, stream>>>(qb, kvb, m_i, invl);
  attn_fused_k<<<dim3(4, Sc / 16, Bc), 256, 0, stream>>>(
      qb, kvb, vT, m_i, invl, attn, opart);
  opart_reduce_k<<<2048, 256, 0, stream>>>(opart, o);

  gemm_bt_k<1><<<dim3(Dc / 128, Mrows / 128), 256, 0, stream>>>(
      o, woT, bo, x, x2, Mrows, Dc, Dc, 0);
  layernorm_k<<<Mrows, 256, 0, stream>>>(x2, ln2g, ln2b, h);
  gemm_bt_k<0><<<dim3(FFc / 128, Mrows / 128), 256, 0, stream>>>(
      h, w1T, b1, nullptr, ff1, Mrows, FFc, Dc, 1);
  gemm_bt_k<1><<<dim3(Dc / 128, Mrows / 128), 256, 0, stream>>>(
      ff1, w2T, b2, x2, out0, Mrows, Dc, FFc, 0);
}

// Round 3
// 1224.610 us; speedup vs baseline: 1.1663x; 1.0440x over previous
//
#include <hip/hip_runtime.h>
#include <hip/hip_bf16.h>

// ---------------------------------------------------------------------------
// TransformerBlock: B=2 S=2048 D=1024 NH=16 HD=64 FF=4096
// Round 4: BN=64 GEMM tile variant for the grid-starved GEMMs (q, o*wo, ffn2:
// 256 -> 512 blocks, 2/CU instead of 1/CU -- m102 shape curve shows the
// 128x128 structure loses ~2.5x at 1 block/CU). No extra traffic vs split-K.
// attn_stats: branchless online-softmax update.
// Attention 2-pass fusion (round 3) unchanged.
// ---------------------------------------------------------------------------

constexpr int Bc = 2, Sc = 2048, Dc = 1024, NHc = 16, FFc = 4096;
constexpr int Mrows = Bc * Sc;              // 4096
constexpr float SCALE_ = 0.125f;            // HD^-0.5
constexpr float EPSc = 1e-5f;
constexpr float L2E = 1.4426950408889634f;
constexpr float SC_L2E = SCALE_ * L2E;

typedef __attribute__((ext_vector_type(8))) short short8;
typedef __attribute__((ext_vector_type(4))) short short4v;
typedef __attribute__((ext_vector_type(4))) float floatx4;

#define DEV static __device__ __forceinline__

DEV short f2b(float f) {                    // fp32 -> bf16 (RNE), raw bits
  union { float f; unsigned u; } v; v.f = f;
  unsigned r = v.u + 0x7FFFu + ((v.u >> 16) & 1u);
  return (short)(r >> 16);
}

DEV floatx4 mfma16(short8 a, short8 b, floatx4 c) {
  return __builtin_amdgcn_mfma_f32_16x16x32_bf16(a, b, c, 0, 0, 0);
}

// Direct global->LDS DMA, 16B per lane. LDS dest is wave-uniform base; HW
// writes base + lane*16. Global src is per-lane.
DEV void load_lds16(const short* g, short* l) {
  __builtin_amdgcn_global_load_lds(
      (const __attribute__((address_space(1))) void*)g,
      (__attribute__((address_space(3))) void*)l, 16, 0, 0);
}

// ---------------------------------------------------------------------------
// Weight cast + transpose: W (K,N) fp32 -> Wt (N,K) bf16
// ---------------------------------------------------------------------------
__global__ __launch_bounds__(256) void cast_transpose_k(
    const float* __restrict__ W, short* __restrict__ Wt, int K, int N) {
  __shared__ float t[32][33];
  int n0 = blockIdx.x * 32, k0 = blockIdx.y * 32;
  int tx = threadIdx.x & 31, ty = threadIdx.x >> 5;
  for (int r = ty; r < 32; r += 8)
    t[r][tx] = W[(size_t)(k0 + r) * N + n0 + tx];
  __syncthreads();
  for (int r = ty; r < 32; r += 8)
    Wt[(size_t)(n0 + r) * K + k0 + tx] = f2b(t[tx][r]);
}

// ---------------------------------------------------------------------------
// LayerNorm over D=1024, fp32 in -> bf16 out. One block (256 thr) per row.
// ---------------------------------------------------------------------------
__global__ __launch_bounds__(256) void layernorm_k(
    const float* __restrict__ x, const float* __restrict__ g,
    const float* __restrict__ bb, short* __restrict__ out) {
  int row = blockIdx.x;
  float4 v = ((const float4*)(x + (size_t)row * Dc))[threadIdx.x];
  float s = v.x + v.y + v.z + v.w;
  float s2 = v.x * v.x + v.y * v.y + v.z * v.z + v.w * v.w;
#pragma unroll
  for (int off = 32; off >= 1; off >>= 1) {
    s += __shfl_xor(s, off);
    s2 += __shfl_xor(s2, off);
  }
  __shared__ float red[8];
  int wave = threadIdx.x >> 6, lane = threadIdx.x & 63;
  if (lane == 0) { red[wave] = s; red[4 + wave] = s2; }
  __syncthreads();
  s = red[0] + red[1] + red[2] + red[3];
  s2 = red[4] + red[5] + red[6] + red[7];
  float mu = s * (1.0f / Dc);
  float var = s2 * (1.0f / Dc) - mu * mu;
  float rstd = rsqrtf(var + EPSc);
  int c = threadIdx.x * 4;
  float4 gv = ((const float4*)g)[threadIdx.x];
  float4 bv = ((const float4*)bb)[threadIdx.x];
  short4v o;
  o.x = f2b((v.x - mu) * rstd * gv.x + bv.x);
  o.y = f2b((v.y - mu) * rstd * gv.y + bv.y);
  o.z = f2b((v.z - mu) * rstd * gv.z + bv.z);
  o.w = f2b((v.w - mu) * rstd * gv.w + bv.w);
  *(short4v*)(out + (size_t)row * Dc + c) = o;
}

// ---------------------------------------------------------------------------
// GEMM: C(MxN) = A(MxK,bf16) @ Bt(NxK,bf16)^T  [+bias] [+resid fp32] [relu]
// m97 structure: 128xBN tile, BK=32, linear LDS, global_load_lds width=16.
// BN=128: 4 waves -> 64x64 quadrants. BN=64: 4 waves -> 64x32 (doubles grid
// for N=1024 outputs: 2 blocks/CU instead of 1).
// ---------------------------------------------------------------------------
template <int OUTF, int BN>
__global__ __launch_bounds__(256) void gemm_bt_k(
    const short* __restrict__ A, const short* __restrict__ Bt,
    const float* __restrict__ bias, const float* __restrict__ resid,
    void* __restrict__ Cout, int M, int N, int K, int relu) {
  constexpr int NJ = (BN == 128) ? 4 : 2;   // 16-col frags per wave
  __shared__ short As[128 * 32];            // 8 KB, linear (global_load_lds)
  __shared__ short Bs[BN * 32];
  int tid = threadIdx.x;
  int wave = tid >> 6, lane = tid & 63, quad = lane >> 4, l16 = lane & 15;
  int m0 = blockIdx.y * 128, n0 = blockIdx.x * BN;
  int wm = (wave & 1) * 64;
  int wn = (wave >> 1) * (BN / 2);
  int lrow = lane >> 2, lcol = (lane & 3) * 8;   // 16 rows x 4 chunks per call
  const short* Ab0 = A + (size_t)(m0 + wave * 32 + lrow) * K + lcol;
  const short* Ab1 = A + (size_t)(m0 + wave * 32 + 16 + lrow) * K + lcol;
  short* Al0 = &As[(wave * 2 + 0) * 512];
  short* Al1 = &As[(wave * 2 + 1) * 512];
  const short* Bb0;
  const short* Bb1 = nullptr;
  short* Bl0;
  short* Bl1 = nullptr;
  if (BN == 128) {
    Bb0 = Bt + (size_t)(n0 + wave * 32 + lrow) * K + lcol;
    Bb1 = Bt + (size_t)(n0 + wave * 32 + 16 + lrow) * K + lcol;
    Bl0 = &Bs[(wave * 2 + 0) * 512];
    Bl1 = &Bs[(wave * 2 + 1) * 512];
  } else {
    Bb0 = Bt + (size_t)(n0 + wave * 16 + lrow) * K + lcol;
    Bl0 = &Bs[wave * 512];
  }
  floatx4 acc[4][NJ] = {};
  for (int k0 = 0; k0 < K; k0 += 32) {
    __syncthreads();                        // prev tile's ds_reads done
    load_lds16(Ab0 + k0, Al0);
    load_lds16(Ab1 + k0, Al1);
    load_lds16(Bb0 + k0, Bl0);
    if (BN == 128) load_lds16(Bb1 + k0, Bl1);
    __syncthreads();                        // vmcnt(0) drain + all waves landed
    short8 af[4], bf[NJ];
#pragma unroll
    for (int i = 0; i < 4; ++i)
      af[i] = *(const short8*)(&As[(wm + i * 16 + l16) * 32 + quad * 8]);
#pragma unroll
    for (int j = 0; j < NJ; ++j)
      bf[j] = *(const short8*)(&Bs[(wn + j * 16 + l16) * 32 + quad * 8]);
#pragma unroll
    for (int i = 0; i < 4; ++i)
#pragma unroll
      for (int j = 0; j < NJ; ++j)
        acc[i][j] = mfma16(af[i], bf[j], acc[i][j]);
  }
#pragma unroll
  for (int i = 0; i < 4; ++i) {
    int row = m0 + wm + i * 16 + quad * 4;
#pragma unroll
    for (int j = 0; j < NJ; ++j) {
      int col = n0 + wn + j * 16 + l16;
      float bv = bias ? bias[col] : 0.0f;
#pragma unroll
      for (int r = 0; r < 4; ++r) {
        float v = acc[i][j][r] + bv;
        if (resid) v += resid[(size_t)(row + r) * N + col];
        if (relu) v = fmaxf(v, 0.0f);
        if (OUTF == 0)
          ((short*)Cout)[(size_t)(row + r) * N + col] = f2b(v);
        else
          ((float*)Cout)[(size_t)(row + r) * N + col] = v;
      }
    }
  }
}

// ---------------------------------------------------------------------------
// vT[b][h][d][m] = kv[b][m][1024 + h*64 + d]   (bf16, for PV B-operand)
// ---------------------------------------------------------------------------
__global__ __launch_bounds__(256) void transpose_v_k(
    const short* __restrict__ kv, short* __restrict__ vT) {
  __shared__ short t[64][65];
  int bh = blockIdx.y, b = bh >> 4, h = bh & 15;
  int m0 = blockIdx.x * 64;
  int c = threadIdx.x & 63, ty = threadIdx.x >> 6;
  for (int r = ty; r < 64; r += 4)
    t[r][c] = kv[(size_t)(b * Sc + m0 + r) * 2048 + 1024 + h * 64 + c];
  __syncthreads();
  for (int dd = ty; dd < 64; dd += 4)
    vT[((size_t)bh * 64 + dd) * Sc + m0 + c] = t[c][dd];
}

// ---------------------------------------------------------------------------
// Attention pass 1: row max (log2-domain, incl. scale) + sumexp2 -> m_i, 1/l
// Branchless online update (divergent branch executed both paths).
// ---------------------------------------------------------------------------
__global__ __launch_bounds__(256) void attn_stats_k(
    const short* __restrict__ q, const short* __restrict__ kv,
    float* __restrict__ m_i, float* __restrict__ inv_l) {
  int bh = blockIdx.y, b = bh >> 4, h = bh & 15;
  int wave = threadIdx.x >> 6, lane = threadIdx.x & 63, quad = lane >> 4,
      l16 = lane & 15;
  int n0 = blockIdx.x * 64 + wave * 16;
  const short* qp = q + (size_t)(b * Sc + n0 + l16) * Dc + h * 64 + quad * 8;
  short8 qf0 = *(const short8*)qp;
  short8 qf1 = *(const short8*)(qp + 32);
  const short* kb = kv + (size_t)b * Sc * 2048 + h * 64 + quad * 8;
  float rm[4], rl[4];
#pragma unroll
  for (int r = 0; r < 4; ++r) { rm[r] = -1e30f; rl[r] = 0.0f; }
  for (int m0 = 0; m0 < Sc; m0 += 16) {
    const short* kp = kb + (size_t)(m0 + l16) * 2048;
    short8 kf0 = *(const short8*)kp;
    short8 kf1 = *(const short8*)(kp + 32);
    floatx4 s = {0.0f, 0.0f, 0.0f, 0.0f};
    s = mfma16(qf0, kf0, s);
    s = mfma16(qf1, kf1, s);
#pragma unroll
    for (int r = 0; r < 4; ++r) {
      float sv = s[r] * SC_L2E;
      float nm = fmaxf(rm[r], sv);
      rl[r] = rl[r] * exp2f(rm[r] - nm) + exp2f(sv - nm);
      rm[r] = nm;
    }
  }
#pragma unroll
  for (int off = 1; off < 16; off <<= 1) {
#pragma unroll
    for (int r = 0; r < 4; ++r) {
      float om = __shfl_xor(rm[r], off);
      float ol = __shfl_xor(rl[r], off);
      float nm = fmaxf(rm[r], om);
      rl[r] = rl[r] * exp2f(rm[r] - nm) + ol * exp2f(om - nm);
      rm[r] = nm;
    }
  }
  if (l16 == 0) {
    int n = n0 + quad * 4;
#pragma unroll
    for (int r = 0; r < 4; ++r) {
      m_i[(size_t)bh * Sc + n + r] = rm[r];
      inv_l[(size_t)bh * Sc + n + r] = 1.0f / rl[r];
    }
  }
}

// ---------------------------------------------------------------------------
// Attention pass 2 (fused): per block (b, 16 n-rows, ALL 16 heads, m-chunk of
// 512). Computes S ONCE per tile: P = exp2(S*c - m)*inv_l (normalized),
// -> fp32 LDS [n][m][h] for coalesced attn stores (1KB/wave-instr)
// -> bf16 per-wave staging for the PV A-fragment; O accumulated per m-chunk,
// partials summed by opart_reduce_k.
// ---------------------------------------------------------------------------
__global__ __launch_bounds__(256) void attn_fused_k(
    const short* __restrict__ q, const short* __restrict__ kv,
    const short* __restrict__ vT, const float* __restrict__ m_i,
    const float* __restrict__ inv_l, float* __restrict__ attn,
    float* __restrict__ opart) {
  constexpr int HP = 20;                    // h-dim pad: 80B rows, f4-aligned
  __shared__ float P[16 * 32 * HP];         // [nn][m][h] 40960 B
  __shared__ short pw[4][16 * 40];          // per-wave bf16 P (A-frag staging)
  __shared__ float sm[16][16], sl[16][16];
  int b = blockIdx.z, mc = blockIdx.x;
  int n0 = blockIdx.y * 16;
  int tid = threadIdx.x;
  int wave = tid >> 6, lane = tid & 63, quad = lane >> 4, l16 = lane & 15;
  {
    int h = tid >> 4, nn = tid & 15;
    sm[h][nn] = m_i[(size_t)(b * 16 + h) * Sc + n0 + nn];
    sl[h][nn] = inv_l[(size_t)(b * 16 + h) * Sc + n0 + nn];
  }
  short8 qf[4][2];
#pragma unroll
  for (int hh = 0; hh < 4; ++hh) {
    const short* qp =
        q + (size_t)(b * Sc + n0 + l16) * Dc + (wave * 4 + hh) * 64 + quad * 8;
    qf[hh][0] = *(const short8*)qp;
    qf[hh][1] = *(const short8*)(qp + 32);
  }
  floatx4 oacc[4][4] = {};
  short* myP = &pw[wave][0];
  __syncthreads();
  int mend = mc * 512 + 512;
  for (int m0 = mc * 512; m0 < mend; m0 += 32) {
#pragma unroll
    for (int hh = 0; hh < 4; ++hh) {
      int h = wave * 4 + hh;
      const short* kb =
          kv + (size_t)(b * Sc + m0 + l16) * 2048 + h * 64 + quad * 8;
#pragma unroll
      for (int ms = 0; ms < 2; ++ms) {
        const short* kp = kb + (size_t)ms * 16 * 2048;
        short8 kf0 = *(const short8*)kp;
        short8 kf1 = *(const short8*)(kp + 32);
        floatx4 s = {0.0f, 0.0f, 0.0f, 0.0f};
        s = mfma16(qf[hh][0], kf0, s);
        s = mfma16(qf[hh][1], kf1, s);
#pragma unroll
        for (int r = 0; r < 4; ++r) {
          int nn = quad * 4 + r;
          float p = exp2f(s[r] * SC_L2E - sm[h][nn]) * sl[h][nn];
          P[(nn * 32 + ms * 16 + l16) * HP + h] = p;
          myP[nn * 40 + ms * 16 + l16] = f2b(p);
        }
      }
      short8 pa = *(const short8*)(&myP[l16 * 40 + quad * 8]);
      const short* vb = vT + ((size_t)(b * 16 + h) * 64) * Sc;
#pragma unroll
      for (int dt = 0; dt < 4; ++dt) {
        short8 vf =
            *(const short8*)(vb + (size_t)(dt * 16 + l16) * Sc + m0 + quad * 8);
        oacc[hh][dt] = mfma16(pa, vf, oacc[hh][dt]);
      }
    }
    __syncthreads();                        // all waves' P[h] slots landed
    size_t base = (((size_t)b * Sc + n0) * Sc + m0) * 16;
    for (int t = tid; t < 2048; t += 256) { // 16n x 32m x 4 h-groups
      int nn = t >> 7, rem = t & 127;
      int ml = rem >> 2, h4 = (rem & 3) * 4;
      float4 v = *(const float4*)&P[(nn * 32 + ml) * HP + h4];
      *(float4*)&attn[base + (size_t)nn * (Sc * 16) + ml * 16 + h4] = v;
    }
    __syncthreads();                        // P free for next m-tile
  }
  float* op = opart + (size_t)mc * ((size_t)Bc * Sc * Dc) +
              ((size_t)b * Sc + n0) * Dc;
#pragma unroll
  for (int hh = 0; hh < 4; ++hh)
#pragma unroll
    for (int dt = 0; dt < 4; ++dt)
#pragma unroll
      for (int r = 0; r < 4; ++r)
        op[(size_t)(quad * 4 + r) * Dc + (wave * 4 + hh) * 64 + dt * 16 + l16] =
            oacc[hh][dt][r];
}

// ---------------------------------------------------------------------------
// O = sum of 4 m-chunk partials, fp32 -> bf16
// ---------------------------------------------------------------------------
__global__ __launch_bounds__(256) void opart_reduce_k(
    const float* __restrict__ op, short* __restrict__ o) {
  const size_t PS = (size_t)Bc * Sc * Dc;   // 4M floats per partial
  const size_t n4 = PS / 4;
  for (size_t i = (size_t)blockIdx.x * 256 + threadIdx.x; i < n4;
       i += (size_t)gridDim.x * 256) {
    float4 a = ((const float4*)op)[i];
    float4 b = ((const float4*)(op + PS))[i];
    float4 c = ((const float4*)(op + 2 * PS))[i];
    float4 d = ((const float4*)(op + 3 * PS))[i];
    short4v s;
    s.x = f2b(a.x + b.x + c.x + d.x);
    s.y = f2b(a.y + b.y + c.y + d.y);
    s.z = f2b(a.z + b.z + c.z + d.z);
    s.w = f2b(a.w + b.w + c.w + d.w);
    ((short4v*)o)[i] = s;
  }
}

// ---------------------------------------------------------------------------
extern "C" void kernel_launch(void* const* d_in, const int* in_sizes, int n_in,
                              void* d_out, int out_size, void* d_ws,
                              size_t ws_size, hipStream_t stream) {
  const float* x = (const float*)d_in[0];
  const float* ln1g = (const float*)d_in[1];
  const float* ln1b = (const float*)d_in[2];
  const float* wq = (const float*)d_in[3];
  const float* wkv = (const float*)d_in[4];
  const float* wo = (const float*)d_in[5];
  const float* bo = (const float*)d_in[6];
  const float* ln2g = (const float*)d_in[7];
  const float* ln2b = (const float*)d_in[8];
  const float* w1 = (const float*)d_in[9];
  const float* b1 = (const float*)d_in[10];
  const float* w2 = (const float*)d_in[11];
  const float* b2 = (const float*)d_in[12];

  char* ws = (char*)d_ws;
  const size_t MB = 1024 * 1024;
  short* wqT  = (short*)(ws + 0 * MB);       // 2 MB
  short* wkvT = (short*)(ws + 2 * MB);       // 4 MB
  short* woT  = (short*)(ws + 6 * MB);       // 2 MB
  short* w1T  = (short*)(ws + 8 * MB);       // 8 MB
  short* w2T  = (short*)(ws + 16 * MB);      // 8 MB
  short* h    = (short*)(ws + 24 * MB);      // 8 MB (reused as h2)
  float* x2   = (float*)(ws + 32 * MB);      // 16 MB
  float* m_i  = (float*)(ws + 48 * MB);      // 256 KB
  float* invl = (float*)(ws + 48 * MB + 256 * 1024);  // 256 KB
  short* o    = (short*)(ws + 49 * MB);      // 8 MB
  short* qb   = (short*)(ws + 57 * MB);      // 8 MB  -+
  short* kvb  = (short*)(ws + 65 * MB);      // 16 MB  | overlaid by ff1 later
  short* vT   = (short*)(ws + 81 * MB);      // 8 MB  -+
  float* opart= (float*)(ws + 96 * MB);      // 64 MB (4 x 16 MB O partials)
  short* ff1  = (short*)(ws + 57 * MB);      // 32 MB (after attention done)

  float* out0 = (float*)d_out;
  float* attn = (float*)d_out + (size_t)Bc * Sc * Dc;

  // weights -> bf16, transposed (N x K)
  cast_transpose_k<<<dim3(Dc / 32, Dc / 32), 256, 0, stream>>>(wq, wqT, Dc, Dc);
  cast_transpose_k<<<dim3(2048 / 32, Dc / 32), 256, 0, stream>>>(wkv, wkvT, Dc, 2048);
  cast_transpose_k<<<dim3(Dc / 32, Dc / 32), 256, 0, stream>>>(wo, woT, Dc, Dc);
  cast_transpose_k<<<dim3(FFc / 32, Dc / 32), 256, 0, stream>>>(w1, w1T, Dc, FFc);
  cast_transpose_k<<<dim3(Dc / 32, FFc / 32), 256, 0, stream>>>(w2, w2T, FFc, Dc);

  layernorm_k<<<Mrows, 256, 0, stream>>>(x, ln1g, ln1b, h);

  gemm_bt_k<0, 64><<<dim3(Dc / 64, Mrows / 128), 256, 0, stream>>>(
      h, wqT, nullptr, nullptr, qb, Mrows, Dc, Dc, 0);
  gemm_bt_k<0, 128><<<dim3(2048 / 128, Mrows / 128), 256, 0, stream>>>(
      h, wkvT, nullptr, nullptr, kvb, Mrows, 2048, Dc, 0);

  transpose_v_k<<<dim3(Sc / 64, Bc * NHc), 256, 0, stream>>>(kvb, vT);
  attn_stats_k<<<dim3(Sc / 64, Bc * NHc), 256, 0, stream>>>(qb, kvb, m_i, invl);
  attn_fused_k<<<dim3(4, Sc / 16, Bc), 256, 0, stream>>>(
      qb, kvb, vT, m_i, invl, attn, opart);
  opart_reduce_k<<<2048, 256, 0, stream>>>(opart, o);

  gemm_bt_k<1, 64><<<dim3(Dc / 64, Mrows / 128), 256, 0, stream>>>(
      o, woT, bo, x, x2, Mrows, Dc, Dc, 0);
  layernorm_k<<<Mrows, 256, 0, stream>>>(x2, ln2g, ln2b, h);
  gemm_bt_k<0, 128><<<dim3(FFc / 128, Mrows / 128), 256, 0, stream>>>(
      h, w1T, b1, nullptr, ff1, Mrows, FFc, Dc, 1);
  gemm_bt_k<1, 64><<<dim3(Dc / 64, Mrows / 128), 256, 0, stream>>>(
      ff1, w2T, b2, x2, out0, Mrows, Dc, FFc, 0);
}

// Round 4
// 1194.538 us; speedup vs baseline: 1.1957x; 1.0252x over previous
//
#include <hip/hip_runtime.h>
#include <hip/hip_bf16.h>

// ---------------------------------------------------------------------------
// TransformerBlock: B=2 S=2048 D=1024 NH=16 HD=64 FF=4096
// Round 5: XCD-locality swizzle for attention (all blocks sharing a K/V chunk
// -> same XCD via bid&7 group decode; L2 captures the 128x reuse that was
// going to L3/HBM). cast_transpose 5->1 launch; transpose_v folded into the
// kv GEMM epilogue (writes vT directly, skips dead kvb V-half).
// 11 dispatches (was 18/16).
// ---------------------------------------------------------------------------

constexpr int Bc = 2, Sc = 2048, Dc = 1024, NHc = 16, FFc = 4096;
constexpr int Mrows = Bc * Sc;              // 4096
constexpr float SCALE_ = 0.125f;            // HD^-0.5
constexpr float EPSc = 1e-5f;
constexpr float L2E = 1.4426950408889634f;
constexpr float SC_L2E = SCALE_ * L2E;

typedef __attribute__((ext_vector_type(8))) short short8;
typedef __attribute__((ext_vector_type(4))) short short4v;
typedef __attribute__((ext_vector_type(4))) float floatx4;

#define DEV static __device__ __forceinline__

DEV short f2b(float f) {                    // fp32 -> bf16 (RNE), raw bits
  union { float f; unsigned u; } v; v.f = f;
  unsigned r = v.u + 0x7FFFu + ((v.u >> 16) & 1u);
  return (short)(r >> 16);
}

DEV floatx4 mfma16(short8 a, short8 b, floatx4 c) {
  return __builtin_amdgcn_mfma_f32_16x16x32_bf16(a, b, c, 0, 0, 0);
}

// Direct global->LDS DMA, 16B per lane. LDS dest is wave-uniform base; HW
// writes base + lane*16. Global src is per-lane.
DEV void load_lds16(const short* g, short* l) {
  __builtin_amdgcn_global_load_lds(
      (const __attribute__((address_space(1))) void*)g,
      (__attribute__((address_space(3))) void*)l, 16, 0, 0);
}

// ---------------------------------------------------------------------------
// All weight casts+transposes in ONE launch. W (K,N) fp32 -> Wt (N,K) bf16.
// Segments (32x32 tiles): wq 1024 | wkv 2048 | wo 1024 | w1 4096 | w2 4096.
// ---------------------------------------------------------------------------
__global__ __launch_bounds__(256) void cast_transpose_all_k(
    const float* __restrict__ wq, const float* __restrict__ wkv,
    const float* __restrict__ wo, const float* __restrict__ w1,
    const float* __restrict__ w2, short* __restrict__ wqT,
    short* __restrict__ wkvT, short* __restrict__ woT,
    short* __restrict__ w1T, short* __restrict__ w2T) {
  __shared__ float t[32][33];
  int bid = blockIdx.x;
  const float* W; short* Wt; int K, N, bx, by;
  if (bid < 1024)      { W = wq;  Wt = wqT;  K = 1024; N = 1024; int u = bid;        bx = u & 31;  by = u >> 5; }
  else if (bid < 3072) { W = wkv; Wt = wkvT; K = 1024; N = 2048; int u = bid - 1024; bx = u & 63;  by = u >> 6; }
  else if (bid < 4096) { W = wo;  Wt = woT;  K = 1024; N = 1024; int u = bid - 3072; bx = u & 31;  by = u >> 5; }
  else if (bid < 8192) { W = w1;  Wt = w1T;  K = 1024; N = 4096; int u = bid - 4096; bx = u & 127; by = u >> 7; }
  else                 { W = w2;  Wt = w2T;  K = 4096; N = 1024; int u = bid - 8192; bx = u & 31;  by = u >> 5; }
  int n0 = bx * 32, k0 = by * 32;
  int tx = threadIdx.x & 31, ty = threadIdx.x >> 5;
  for (int r = ty; r < 32; r += 8)
    t[r][tx] = W[(size_t)(k0 + r) * N + n0 + tx];
  __syncthreads();
  for (int r = ty; r < 32; r += 8)
    Wt[(size_t)(n0 + r) * K + k0 + tx] = f2b(t[tx][r]);
}

// ---------------------------------------------------------------------------
// LayerNorm over D=1024, fp32 in -> bf16 out. One block (256 thr) per row.
// ---------------------------------------------------------------------------
__global__ __launch_bounds__(256) void layernorm_k(
    const float* __restrict__ x, const float* __restrict__ g,
    const float* __restrict__ bb, short* __restrict__ out) {
  int row = blockIdx.x;
  float4 v = ((const float4*)(x + (size_t)row * Dc))[threadIdx.x];
  float s = v.x + v.y + v.z + v.w;
  float s2 = v.x * v.x + v.y * v.y + v.z * v.z + v.w * v.w;
#pragma unroll
  for (int off = 32; off >= 1; off >>= 1) {
    s += __shfl_xor(s, off);
    s2 += __shfl_xor(s2, off);
  }
  __shared__ float red[8];
  int wave = threadIdx.x >> 6, lane = threadIdx.x & 63;
  if (lane == 0) { red[wave] = s; red[4 + wave] = s2; }
  __syncthreads();
  s = red[0] + red[1] + red[2] + red[3];
  s2 = red[4] + red[5] + red[6] + red[7];
  float mu = s * (1.0f / Dc);
  float var = s2 * (1.0f / Dc) - mu * mu;
  float rstd = rsqrtf(var + EPSc);
  int c = threadIdx.x * 4;
  float4 gv = ((const float4*)g)[threadIdx.x];
  float4 bv = ((const float4*)bb)[threadIdx.x];
  short4v o;
  o.x = f2b((v.x - mu) * rstd * gv.x + bv.x);
  o.y = f2b((v.y - mu) * rstd * gv.y + bv.y);
  o.z = f2b((v.z - mu) * rstd * gv.z + bv.z);
  o.w = f2b((v.w - mu) * rstd * gv.w + bv.w);
  *(short4v*)(out + (size_t)row * Dc + c) = o;
}

// ---------------------------------------------------------------------------
// GEMM: C(MxN) = A(MxK,bf16) @ Bt(NxK,bf16)^T  [+bias] [+resid fp32] [relu]
// m97 structure: 128xBN tile, BK=32, linear LDS, global_load_lds width=16.
// vTout (kv GEMM only): V-half blocks (n0>=1024) write transposed bf16 to
// vT[(b*16+h)*64+d][m] instead of kvb (which is never read for V).
// ---------------------------------------------------------------------------
template <int OUTF, int BN>
__global__ __launch_bounds__(256) void gemm_bt_k(
    const short* __restrict__ A, const short* __restrict__ Bt,
    const float* __restrict__ bias, const float* __restrict__ resid,
    void* __restrict__ Cout, int M, int N, int K, int relu,
    short* __restrict__ vTout) {
  constexpr int NJ = (BN == 128) ? 4 : 2;   // 16-col frags per wave
  __shared__ short As[128 * 32];            // 8 KB, linear (global_load_lds)
  __shared__ short Bs[BN * 32];
  int tid = threadIdx.x;
  int wave = tid >> 6, lane = tid & 63, quad = lane >> 4, l16 = lane & 15;
  int m0 = blockIdx.y * 128, n0 = blockIdx.x * BN;
  int wm = (wave & 1) * 64;
  int wn = (wave >> 1) * (BN / 2);
  int lrow = lane >> 2, lcol = (lane & 3) * 8;   // 16 rows x 4 chunks per call
  const short* Ab0 = A + (size_t)(m0 + wave * 32 + lrow) * K + lcol;
  const short* Ab1 = A + (size_t)(m0 + wave * 32 + 16 + lrow) * K + lcol;
  short* Al0 = &As[(wave * 2 + 0) * 512];
  short* Al1 = &As[(wave * 2 + 1) * 512];
  const short* Bb0;
  const short* Bb1 = nullptr;
  short* Bl0;
  short* Bl1 = nullptr;
  if (BN == 128) {
    Bb0 = Bt + (size_t)(n0 + wave * 32 + lrow) * K + lcol;
    Bb1 = Bt + (size_t)(n0 + wave * 32 + 16 + lrow) * K + lcol;
    Bl0 = &Bs[(wave * 2 + 0) * 512];
    Bl1 = &Bs[(wave * 2 + 1) * 512];
  } else {
    Bb0 = Bt + (size_t)(n0 + wave * 16 + lrow) * K + lcol;
    Bl0 = &Bs[wave * 512];
  }
  floatx4 acc[4][NJ] = {};
  for (int k0 = 0; k0 < K; k0 += 32) {
    __syncthreads();                        // prev tile's ds_reads done
    load_lds16(Ab0 + k0, Al0);
    load_lds16(Ab1 + k0, Al1);
    load_lds16(Bb0 + k0, Bl0);
    if (BN == 128) load_lds16(Bb1 + k0, Bl1);
    __syncthreads();                        // vmcnt(0) drain + all waves landed
    short8 af[4], bf[NJ];
#pragma unroll
    for (int i = 0; i < 4; ++i)
      af[i] = *(const short8*)(&As[(wm + i * 16 + l16) * 32 + quad * 8]);
#pragma unroll
    for (int j = 0; j < NJ; ++j)
      bf[j] = *(const short8*)(&Bs[(wn + j * 16 + l16) * 32 + quad * 8]);
#pragma unroll
    for (int i = 0; i < 4; ++i)
#pragma unroll
      for (int j = 0; j < NJ; ++j)
        acc[i][j] = mfma16(af[i], bf[j], acc[i][j]);
  }
  if (vTout != nullptr && n0 >= 1024) {     // V half -> transposed bf16 store
#pragma unroll
    for (int i = 0; i < 4; ++i) {
      int row = m0 + wm + i * 16 + quad * 4;
      int bb = row >> 11, mloc = row & 2047;
#pragma unroll
      for (int j = 0; j < NJ; ++j) {
        int dg = n0 + wn + j * 16 + l16 - 1024;
        short4v pk;
        pk.x = f2b(acc[i][j][0]);
        pk.y = f2b(acc[i][j][1]);
        pk.z = f2b(acc[i][j][2]);
        pk.w = f2b(acc[i][j][3]);
        *(short4v*)(vTout +
                    ((size_t)(bb * 16 + (dg >> 6)) * 64 + (dg & 63)) * Sc +
                    mloc) = pk;
      }
    }
    return;
  }
#pragma unroll
  for (int i = 0; i < 4; ++i) {
    int row = m0 + wm + i * 16 + quad * 4;
#pragma unroll
    for (int j = 0; j < NJ; ++j) {
      int col = n0 + wn + j * 16 + l16;
      float bv = bias ? bias[col] : 0.0f;
#pragma unroll
      for (int r = 0; r < 4; ++r) {
        float v = acc[i][j][r] + bv;
        if (resid) v += resid[(size_t)(row + r) * N + col];
        if (relu) v = fmaxf(v, 0.0f);
        if (OUTF == 0)
          ((short*)Cout)[(size_t)(row + r) * N + col] = f2b(v);
        else
          ((float*)Cout)[(size_t)(row + r) * N + col] = v;
      }
    }
  }
}

// ---------------------------------------------------------------------------
// Attention pass 1: row max (log2-domain, incl. scale) + sumexp2 -> m_i, 1/l
// 1-D grid, XCD-group decode: blocks sharing a head's K stream co-reside on
// one XCD (bid&7 -> 4 bh per XCD; 1 MB K working set fits the 4 MB L2).
// ---------------------------------------------------------------------------
__global__ __launch_bounds__(256) void attn_stats_k(
    const short* __restrict__ q, const short* __restrict__ kv,
    float* __restrict__ m_i, float* __restrict__ inv_l) {
  int bid = blockIdx.x;                     // 1024
  int r_ = bid >> 3;                        // 0..127
  int bh = (bid & 7) * 4 + (r_ >> 5);       // 0..31, grouped per XCD
  int nb = r_ & 31;                         // 0..31
  int b = bh >> 4, h = bh & 15;
  int wave = threadIdx.x >> 6, lane = threadIdx.x & 63, quad = lane >> 4,
      l16 = lane & 15;
  int n0 = nb * 64 + wave * 16;
  const short* qp = q + (size_t)(b * Sc + n0 + l16) * Dc + h * 64 + quad * 8;
  short8 qf0 = *(const short8*)qp;
  short8 qf1 = *(const short8*)(qp + 32);
  const short* kb = kv + (size_t)b * Sc * 2048 + h * 64 + quad * 8;
  float rm[4], rl[4];
#pragma unroll
  for (int r = 0; r < 4; ++r) { rm[r] = -1e30f; rl[r] = 0.0f; }
  for (int m0 = 0; m0 < Sc; m0 += 16) {
    const short* kp = kb + (size_t)(m0 + l16) * 2048;
    short8 kf0 = *(const short8*)kp;
    short8 kf1 = *(const short8*)(kp + 32);
    floatx4 s = {0.0f, 0.0f, 0.0f, 0.0f};
    s = mfma16(qf0, kf0, s);
    s = mfma16(qf1, kf1, s);
#pragma unroll
    for (int r = 0; r < 4; ++r) {
      float sv = s[r] * SC_L2E;
      float nm = fmaxf(rm[r], sv);
      rl[r] = rl[r] * exp2f(rm[r] - nm) + exp2f(sv - nm);
      rm[r] = nm;
    }
  }
#pragma unroll
  for (int off = 1; off < 16; off <<= 1) {
#pragma unroll
    for (int r = 0; r < 4; ++r) {
      float om = __shfl_xor(rm[r], off);
      float ol = __shfl_xor(rl[r], off);
      float nm = fmaxf(rm[r], om);
      rl[r] = rl[r] * exp2f(rm[r] - nm) + ol * exp2f(om - nm);
      rm[r] = nm;
    }
  }
  if (l16 == 0) {
    int n = n0 + quad * 4;
#pragma unroll
    for (int r = 0; r < 4; ++r) {
      m_i[(size_t)bh * Sc + n + r] = rm[r];
      inv_l[(size_t)bh * Sc + n + r] = 1.0f / rl[r];
    }
  }
}

// ---------------------------------------------------------------------------
// Attention pass 2 (fused): per block (b, 16 n-rows, ALL 16 heads, m-chunk of
// 512). 1-D grid, XCD-group decode: the 128 n-blocks sharing one (b,mc) K/V
// chunk (~2 MB) land on one XCD -> L2-local 128x reuse.
// P = exp2(S*c - m)*inv_l -> fp32 LDS [n][m][h] for coalesced attn stores
// -> bf16 per-wave staging for PV A-frag; O partials summed by opart_reduce_k.
// ---------------------------------------------------------------------------
__global__ __launch_bounds__(256) void attn_fused_k(
    const short* __restrict__ q, const short* __restrict__ kv,
    const short* __restrict__ vT, const float* __restrict__ m_i,
    const float* __restrict__ inv_l, float* __restrict__ attn,
    float* __restrict__ opart) {
  constexpr int HP = 20;                    // h-dim pad: 80B rows, f4-aligned
  __shared__ float P[16 * 32 * HP];         // [nn][m][h] 40960 B
  __shared__ short pw[4][16 * 40];          // per-wave bf16 P (A-frag staging)
  __shared__ float sm[16][16], sl[16][16];
  int bid = blockIdx.x;                     // 1024
  int g = bid & 7;                          // XCD group = (b, mc)
  int b = g >> 2, mc = g & 3;
  int n0 = (bid >> 3) * 16;                 // 0..127 n-blocks
  int tid = threadIdx.x;
  int wave = tid >> 6, lane = tid & 63, quad = lane >> 4, l16 = lane & 15;
  {
    int h = tid >> 4, nn = tid & 15;
    sm[h][nn] = m_i[(size_t)(b * 16 + h) * Sc + n0 + nn];
    sl[h][nn] = inv_l[(size_t)(b * 16 + h) * Sc + n0 + nn];
  }
  short8 qf[4][2];
#pragma unroll
  for (int hh = 0; hh < 4; ++hh) {
    const short* qp =
        q + (size_t)(b * Sc + n0 + l16) * Dc + (wave * 4 + hh) * 64 + quad * 8;
    qf[hh][0] = *(const short8*)qp;
    qf[hh][1] = *(const short8*)(qp + 32);
  }
  floatx4 oacc[4][4] = {};
  short* myP = &pw[wave][0];
  __syncthreads();
  int mend = mc * 512 + 512;
  for (int m0 = mc * 512; m0 < mend; m0 += 32) {
#pragma unroll
    for (int hh = 0; hh < 4; ++hh) {
      int h = wave * 4 + hh;
      const short* kb =
          kv + (size_t)(b * Sc + m0 + l16) * 2048 + h * 64 + quad * 8;
#pragma unroll
      for (int ms = 0; ms < 2; ++ms) {
        const short* kp = kb + (size_t)ms * 16 * 2048;
        short8 kf0 = *(const short8*)kp;
        short8 kf1 = *(const short8*)(kp + 32);
        floatx4 s = {0.0f, 0.0f, 0.0f, 0.0f};
        s = mfma16(qf[hh][0], kf0, s);
        s = mfma16(qf[hh][1], kf1, s);
#pragma unroll
        for (int r = 0; r < 4; ++r) {
          int nn = quad * 4 + r;
          float p = exp2f(s[r] * SC_L2E - sm[h][nn]) * sl[h][nn];
          P[(nn * 32 + ms * 16 + l16) * HP + h] = p;
          myP[nn * 40 + ms * 16 + l16] = f2b(p);
        }
      }
      short8 pa = *(const short8*)(&myP[l16 * 40 + quad * 8]);
      const short* vb = vT + ((size_t)(b * 16 + h) * 64) * Sc;
#pragma unroll
      for (int dt = 0; dt < 4; ++dt) {
        short8 vf =
            *(const short8*)(vb + (size_t)(dt * 16 + l16) * Sc + m0 + quad * 8);
        oacc[hh][dt] = mfma16(pa, vf, oacc[hh][dt]);
      }
    }
    __syncthreads();                        // all waves' P[h] slots landed
    size_t base = (((size_t)b * Sc + n0) * Sc + m0) * 16;
    for (int t = tid; t < 2048; t += 256) { // 16n x 32m x 4 h-groups
      int nn = t >> 7, rem = t & 127;
      int ml = rem >> 2, h4 = (rem & 3) * 4;
      float4 v = *(const float4*)&P[(nn * 32 + ml) * HP + h4];
      *(float4*)&attn[base + (size_t)nn * (Sc * 16) + ml * 16 + h4] = v;
    }
    __syncthreads();                        // P free for next m-tile
  }
  float* op = opart + (size_t)mc * ((size_t)Bc * Sc * Dc) +
              ((size_t)b * Sc + n0) * Dc;
#pragma unroll
  for (int hh = 0; hh < 4; ++hh)
#pragma unroll
    for (int dt = 0; dt < 4; ++dt)
#pragma unroll
      for (int r = 0; r < 4; ++r)
        op[(size_t)(quad * 4 + r) * Dc + (wave * 4 + hh) * 64 + dt * 16 + l16] =
            oacc[hh][dt][r];
}

// ---------------------------------------------------------------------------
// O = sum of 4 m-chunk partials, fp32 -> bf16
// ---------------------------------------------------------------------------
__global__ __launch_bounds__(256) void opart_reduce_k(
    const float* __restrict__ op, short* __restrict__ o) {
  const size_t PS = (size_t)Bc * Sc * Dc;   // 4M floats per partial
  const size_t n4 = PS / 4;
  for (size_t i = (size_t)blockIdx.x * 256 + threadIdx.x; i < n4;
       i += (size_t)gridDim.x * 256) {
    float4 a = ((const float4*)op)[i];
    float4 b = ((const float4*)(op + PS))[i];
    float4 c = ((const float4*)(op + 2 * PS))[i];
    float4 d = ((const float4*)(op + 3 * PS))[i];
    short4v s;
    s.x = f2b(a.x + b.x + c.x + d.x);
    s.y = f2b(a.y + b.y + c.y + d.y);
    s.z = f2b(a.z + b.z + c.z + d.z);
    s.w = f2b(a.w + b.w + c.w + d.w);
    ((short4v*)o)[i] = s;
  }
}

// ---------------------------------------------------------------------------
extern "C" void kernel_launch(void* const* d_in, const int* in_sizes, int n_in,
                              void* d_out, int out_size, void* d_ws,
                              size_t ws_size, hipStream_t stream) {
  const float* x = (const float*)d_in[0];
  const float* ln1g = (const float*)d_in[1];
  const float* ln1b = (const float*)d_in[2];
  const float* wq = (const float*)d_in[3];
  const float* wkv = (const float*)d_in[4];
  const float* wo = (const float*)d_in[5];
  const float* bo = (const float*)d_in[6];
  const float* ln2g = (const float*)d_in[7];
  const float* ln2b = (const float*)d_in[8];
  const float* w1 = (const float*)d_in[9];
  const float* b1 = (const float*)d_in[10];
  const float* w2 = (const float*)d_in[11];
  const float* b2 = (const float*)d_in[12];

  char* ws = (char*)d_ws;
  const size_t MB = 1024 * 1024;
  short* wqT  = (short*)(ws + 0 * MB);       // 2 MB
  short* wkvT = (short*)(ws + 2 * MB);       // 4 MB
  short* woT  = (short*)(ws + 6 * MB);       // 2 MB
  short* w1T  = (short*)(ws + 8 * MB);       // 8 MB
  short* w2T  = (short*)(ws + 16 * MB);      // 8 MB
  short* h    = (short*)(ws + 24 * MB);      // 8 MB (reused as h2)
  float* x2   = (float*)(ws + 32 * MB);      // 16 MB
  float* m_i  = (float*)(ws + 48 * MB);      // 256 KB
  float* invl = (float*)(ws + 48 * MB + 256 * 1024);  // 256 KB
  short* o    = (short*)(ws + 49 * MB);      // 8 MB
  short* qb   = (short*)(ws + 57 * MB);      // 8 MB  -+
  short* kvb  = (short*)(ws + 65 * MB);      // 16 MB  | overlaid by ff1 later
  short* vT   = (short*)(ws + 81 * MB);      // 8 MB  -+
  float* opart= (float*)(ws + 96 * MB);      // 64 MB (4 x 16 MB O partials)
  short* ff1  = (short*)(ws + 57 * MB);      // 32 MB (after attention done)

  float* out0 = (float*)d_out;
  float* attn = (float*)d_out + (size_t)Bc * Sc * Dc;

  // all weights -> bf16, transposed (N x K), one launch
  cast_transpose_all_k<<<12288, 256, 0, stream>>>(
      wq, wkv, wo, w1, w2, wqT, wkvT, woT, w1T, w2T);

  layernorm_k<<<Mrows, 256, 0, stream>>>(x, ln1g, ln1b, h);

  gemm_bt_k<0, 64><<<dim3(Dc / 64, Mrows / 128), 256, 0, stream>>>(
      h, wqT, nullptr, nullptr, qb, Mrows, Dc, Dc, 0, nullptr);
  // kv GEMM: K-half -> kvb, V-half -> vT (transposed in epilogue)
  gemm_bt_k<0, 128><<<dim3(2048 / 128, Mrows / 128), 256, 0, stream>>>(
      h, wkvT, nullptr, nullptr, kvb, Mrows, 2048, Dc, 0, vT);

  attn_stats_k<<<1024, 256, 0, stream>>>(qb, kvb, m_i, invl);
  attn_fused_k<<<1024, 256, 0, stream>>>(qb, kvb, vT, m_i, invl, attn, opart);
  opart_reduce_k<<<2048, 256, 0, stream>>>(opart, o);

  gemm_bt_k<1, 64><<<dim3(Dc / 64, Mrows / 128), 256, 0, stream>>>(
      o, woT, bo, x, x2, Mrows, Dc, Dc, 0, nullptr);
  layernorm_k<<<Mrows, 256, 0, stream>>>(x2, ln2g, ln2b, h);
  gemm_bt_k<0, 128><<<dim3(FFc / 128, Mrows / 128), 256, 0, stream>>>(
      h, w1T, b1, nullptr, ff1, Mrows, FFc, Dc, 1, nullptr);
  gemm_bt_k<1, 64><<<dim3(Dc / 64, Mrows / 128), 256, 0, stream>>>(
      ff1, w2T, b2, x2, out0, Mrows, Dc, FFc, 0, nullptr);
}